// Round 3
// baseline (133.060 us; speedup 1.0000x reference)
//
#include <hip/hip_runtime.h>

// TRecPolicy fused per-row kernel, round 3: Padé(5,4) rational activations with
// one shared v_rcp per packed pair (trans ops per row: 352 -> 88).

typedef float v2f __attribute__((ext_vector_type(2)));

__device__ __forceinline__ v2f mk2(float a, float b) { v2f r; r.x = a; r.y = b; return r; }
__device__ __forceinline__ v2f spl(float s) { return mk2(s, s); }
__device__ __forceinline__ v2f fma2(v2f a, v2f b, v2f c) { return __builtin_elementwise_fma(a, b, c); }
__device__ __forceinline__ float frcp(float x) { return __builtin_amdgcn_rcpf(x); }
__device__ __forceinline__ float fclamp(float x, float c) { return __builtin_amdgcn_fmed3f(x, -c, c); }

// tanh pair via Padé(5,4): x(945+105t+t^2)/(945+420t+15t^2), t=x^2, |x| clamped to 3.7.
// One v_rcp serves both lanes: r = rcp(d0*d1); 1/d0 = d1*r, 1/d1 = d0*r.
__device__ __forceinline__ v2f tanh2(v2f x) {
    v2f xc = mk2(fclamp(x.x, 3.7f), fclamp(x.y, 3.7f));   // v_med3_f32
    v2f t = xc * xc;
    v2f num = fma2(t, t + spl(105.0f), spl(945.0f)) * xc;
    v2f den = fma2(t, fma2(t, spl(15.0f), spl(420.0f)), spl(945.0f));
    float r = frcp(den.x * den.y);
    v2f rec = mk2(den.y, den.x) * spl(r);
    return num * rec;
}
// sigmoid pair: 0.5 + x(15120+420t+t^2)/(60480+6720t+60t^2), |x| clamped to 7.4.
__device__ __forceinline__ v2f sig2(v2f x) {
    v2f xc = mk2(fclamp(x.x, 7.4f), fclamp(x.y, 7.4f));
    v2f t = xc * xc;
    v2f num = fma2(t, t + spl(420.0f), spl(15120.0f)) * xc;
    v2f den = fma2(t, fma2(t, spl(60.0f), spl(6720.0f)), spl(60480.0f));
    float r = frcp(den.x * den.y);
    v2f rec = mk2(den.y, den.x) * spl(r);
    return fma2(num, rec, spl(0.5f));
}

// acc += W[k..k+1][:] . [a,b]  (row-major, row stride 4, packed over output rows k,k+1)
__device__ __forceinline__ v2f dot4(const float* __restrict__ w, int k,
                                    v2f a, v2f b, v2f acc) {
    acc = fma2(spl(a.x), mk2(w[4 * k + 0], w[4 * k + 4]), acc);
    acc = fma2(spl(a.y), mk2(w[4 * k + 1], w[4 * k + 5]), acc);
    acc = fma2(spl(b.x), mk2(w[4 * k + 2], w[4 * k + 6]), acc);
    acc = fma2(spl(b.y), mk2(w[4 * k + 3], w[4 * k + 7]), acc);
    return acc;
}

__global__ void __launch_bounds__(256) trec_kernel(
    const float* __restrict__ x,
    const float* __restrict__ w_ih_up, const float* __restrict__ w_hh_up,
    const float* __restrict__ b_ih_up, const float* __restrict__ b_hh_up,
    const float* __restrict__ w1, const float* __restrict__ b1,
    const float* __restrict__ w2, const float* __restrict__ b2,
    const float* __restrict__ w_ih_dn, const float* __restrict__ w_hh_dn,
    const float* __restrict__ b_ih_dn, const float* __restrict__ b_hh_dn,
    const float* __restrict__ w_out, const float* __restrict__ b_out,
    float* __restrict__ out, int n)
{
    int row = blockIdx.x * blockDim.x + threadIdx.x;
    if (row >= n) return;

    // ---- load 18-float row as 9x float2 ----
    float xv[18];
    {
        const float2* xp = reinterpret_cast<const float2*>(x + (size_t)row * 18u);
        #pragma unroll
        for (int k = 0; k < 9; ++k) {
            float2 v = xp[k];
            xv[2 * k] = v.x;
            xv[2 * k + 1] = v.y;
        }
    }

    // ---- hoisted uniform bias pairs ----
    v2f bsum_up[4], bsum_dn[4];          // r,z gates: b_ih + b_hh pre-summed
    #pragma unroll
    for (int p = 0; p < 4; ++p) {
        bsum_up[p] = mk2(b_ih_up[2 * p], b_ih_up[2 * p + 1]) + mk2(b_hh_up[2 * p], b_hh_up[2 * p + 1]);
        bsum_dn[p] = mk2(b_ih_dn[2 * p], b_ih_dn[2 * p + 1]) + mk2(b_hh_dn[2 * p], b_hh_dn[2 * p + 1]);
    }
    const v2f bihnA_up = mk2(b_ih_up[8], b_ih_up[9]),  bihnB_up = mk2(b_ih_up[10], b_ih_up[11]);
    const v2f bhhnA_up = mk2(b_hh_up[8], b_hh_up[9]),  bhhnB_up = mk2(b_hh_up[10], b_hh_up[11]);
    const v2f bihnA_dn = mk2(b_ih_dn[8], b_ih_dn[9]),  bihnB_dn = mk2(b_ih_dn[10], b_ih_dn[11]);
    const v2f bhhnA_dn = mk2(b_hh_dn[8], b_hh_dn[9]),  bhhnB_dn = mk2(b_hh_dn[10], b_hh_dn[11]);

    v2f hA = spl(0.f), hB = spl(0.f);
    v2f hupA[7], hupB[7];

    // ---- up GRU: i = 6..0, xi = [j[i], jd[i]] ----
    #pragma unroll
    for (int s = 0; s < 7; ++s) {
        const int i = 6 - s;
        const v2f X0 = spl(xv[4 + i]);
        const v2f X1 = spl(xv[11 + i]);

        v2f rz[4];
        #pragma unroll
        for (int p = 0; p < 4; ++p) {          // r pairs (k=0,2), z pairs (k=4,6)
            const int k = 2 * p;
            v2f acc = bsum_up[p];
            acc = fma2(X0, mk2(w_ih_up[2 * k], w_ih_up[2 * k + 2]), acc);
            acc = fma2(X1, mk2(w_ih_up[2 * k + 1], w_ih_up[2 * k + 3]), acc);
            acc = dot4(w_hh_up, k, hA, hB, acc);
            rz[p] = acc;
        }
        v2f rA = sig2(rz[0]), rB = sig2(rz[1]);
        v2f zA = sig2(rz[2]), zB = sig2(rz[3]);

        // n gates: gi and gh kept separate for r * gh_n
        v2f giA = bihnA_up, giB = bihnB_up;
        giA = fma2(X0, mk2(w_ih_up[16], w_ih_up[18]), giA);
        giA = fma2(X1, mk2(w_ih_up[17], w_ih_up[19]), giA);
        giB = fma2(X0, mk2(w_ih_up[20], w_ih_up[22]), giB);
        giB = fma2(X1, mk2(w_ih_up[21], w_ih_up[23]), giB);
        v2f ghA = dot4(w_hh_up, 8,  hA, hB, bhhnA_up);
        v2f ghB = dot4(w_hh_up, 10, hA, hB, bhhnB_up);
        v2f nA = tanh2(fma2(rA, ghA, giA));
        v2f nB = tanh2(fma2(rB, ghB, giB));

        hA = fma2(zA, hA - nA, nA);            // (1-z)*n + z*h
        hB = fma2(zB, hB - nB, nB);
        hupA[s] = hA; hupB[s] = hB;
    }

    // ---- MLP: tanh([obs,h] @ w1.T + b1) -> tanh(@ w2.T + b2) ----
    {
        float in8[8] = { xv[0], xv[1], xv[2], xv[3], hA.x, hA.y, hB.x, hB.y };
        v2f t1A, t1B;
        {
            v2f a0 = mk2(b1[0], b1[1]), a1 = mk2(b1[2], b1[3]);
            #pragma unroll
            for (int d = 0; d < 8; ++d) {
                a0 = fma2(spl(in8[d]), mk2(w1[d], w1[8 + d]), a0);
                a1 = fma2(spl(in8[d]), mk2(w1[16 + d], w1[24 + d]), a1);
            }
            t1A = tanh2(a0); t1B = tanh2(a1);
        }
        v2f a0 = dot4(w2, 0, t1A, t1B, mk2(b2[0], b2[1]));
        v2f a1 = dot4(w2, 2, t1A, t1B, mk2(b2[2], b2[3]));
        hA = tanh2(a0); hB = tanh2(a1);
    }

    // ---- down GRU: i = 0..6, xi = hup[i]; act = [h, j[i]] @ w_out.T + b_out ----
    const float wo0 = w_out[0], wo1 = w_out[1], wo2 = w_out[2], wo3 = w_out[3], wo4 = w_out[4];
    const float bo = b_out[0];
    float acts[7];
    #pragma unroll
    for (int i = 0; i < 7; ++i) {
        const v2f xiA = hupA[i], xiB = hupB[i];

        v2f rz[4];
        #pragma unroll
        for (int p = 0; p < 4; ++p) {
            const int k = 2 * p;
            v2f acc = bsum_dn[p];
            acc = dot4(w_ih_dn, k, xiA, xiB, acc);
            acc = dot4(w_hh_dn, k, hA, hB, acc);
            rz[p] = acc;
        }
        v2f rA = sig2(rz[0]), rB = sig2(rz[1]);
        v2f zA = sig2(rz[2]), zB = sig2(rz[3]);

        v2f giA = dot4(w_ih_dn, 8,  xiA, xiB, bihnA_dn);
        v2f giB = dot4(w_ih_dn, 10, xiA, xiB, bihnB_dn);
        v2f ghA = dot4(w_hh_dn, 8,  hA, hB, bhhnA_dn);
        v2f ghB = dot4(w_hh_dn, 10, hA, hB, bhhnB_dn);
        v2f nA = tanh2(fma2(rA, ghA, giA));
        v2f nB = tanh2(fma2(rB, ghB, giB));

        hA = fma2(zA, hA - nA, nA);
        hB = fma2(zB, hB - nB, nB);

        v2f t = fma2(hA, mk2(wo0, wo1), mk2(bo, 0.f));
        t = fma2(hB, mk2(wo2, wo3), t);
        acts[i] = fmaf(xv[4 + i], wo4, t.x + t.y);
    }

    // ---- store (n x 7, row-major) ----
    float* op = out + (size_t)row * 7u;
    #pragma unroll
    for (int i = 0; i < 7; ++i) op[i] = acts[i];
}

extern "C" void kernel_launch(void* const* d_in, const int* in_sizes, int n_in,
                              void* d_out, int out_size, void* d_ws, size_t ws_size,
                              hipStream_t stream)
{
    const float* x       = (const float*)d_in[0];
    const float* w_ih_up = (const float*)d_in[1];
    const float* w_hh_up = (const float*)d_in[2];
    const float* b_ih_up = (const float*)d_in[3];
    const float* b_hh_up = (const float*)d_in[4];
    const float* w1      = (const float*)d_in[5];
    const float* b1      = (const float*)d_in[6];
    const float* w2      = (const float*)d_in[7];
    const float* b2      = (const float*)d_in[8];
    const float* w_ih_dn = (const float*)d_in[9];
    const float* w_hh_dn = (const float*)d_in[10];
    const float* b_ih_dn = (const float*)d_in[11];
    const float* b_hh_dn = (const float*)d_in[12];
    const float* w_out   = (const float*)d_in[13];
    const float* b_out   = (const float*)d_in[14];
    float* out = (float*)d_out;

    const int n = in_sizes[0] / 18;
    const int block = 256;
    const int grid = (n + block - 1) / block;

    trec_kernel<<<grid, block, 0, stream>>>(
        x, w_ih_up, w_hh_up, b_ih_up, b_hh_up,
        w1, b1, w2, b2,
        w_ih_dn, w_hh_dn, b_ih_dn, b_hh_dn,
        w_out, b_out, out, n);
}

// Round 4
// 132.007 us; speedup vs baseline: 1.0080x; 1.0080x over previous
//
#include <hip/hip_runtime.h>

// TRecPolicy fused per-row kernel, round 4: round-2 exp-based packed math
// (fastest so far) + 2 rows per thread for doubled per-wave ILP.
// Row pair: (tid, tid + half) so both streams stay stride-72B coalesced.

typedef float v2f __attribute__((ext_vector_type(2)));

__device__ __forceinline__ v2f mk2(float a, float b) { v2f r; r.x = a; r.y = b; return r; }
__device__ __forceinline__ v2f spl(float s) { return mk2(s, s); }
__device__ __forceinline__ v2f fma2(v2f a, v2f b, v2f c) { return __builtin_elementwise_fma(a, b, c); }

__device__ __forceinline__ float fexp2(float x) {
#if __has_builtin(__builtin_amdgcn_exp2f)
    return __builtin_amdgcn_exp2f(x);          // v_exp_f32 (2^x)
#else
    return __expf(0.6931471805599453f * x);
#endif
}
__device__ __forceinline__ float frcp(float x) { return __builtin_amdgcn_rcpf(x); }

#define LOG2E 1.44269504088896f

// sigmoid pair: 1/(1+2^(-x*log2e))
__device__ __forceinline__ v2f sig2(v2f g) {
    v2f t = g * spl(-LOG2E);
    v2f e = mk2(fexp2(t.x), fexp2(t.y));
    v2f d = e + spl(1.0f);
    return mk2(frcp(d.x), frcp(d.y));
}
// tanh pair: 2/(1+2^(-2x*log2e)) - 1
__device__ __forceinline__ v2f tanh2(v2f g) {
    v2f t = g * spl(-2.0f * LOG2E);
    v2f e = mk2(fexp2(t.x), fexp2(t.y));
    v2f d = e + spl(1.0f);
    v2f r = mk2(frcp(d.x), frcp(d.y));
    return fma2(r, spl(2.0f), spl(-1.0f));
}

// acc += W[k..k+1][:] . [a,b]  (row-major, row stride 4, packed over output rows k,k+1)
__device__ __forceinline__ v2f dot4(const float* __restrict__ w, int k,
                                    v2f a, v2f b, v2f acc) {
    acc = fma2(spl(a.x), mk2(w[4 * k + 0], w[4 * k + 4]), acc);
    acc = fma2(spl(a.y), mk2(w[4 * k + 1], w[4 * k + 5]), acc);
    acc = fma2(spl(b.x), mk2(w[4 * k + 2], w[4 * k + 6]), acc);
    acc = fma2(spl(b.y), mk2(w[4 * k + 3], w[4 * k + 7]), acc);
    return acc;
}

__global__ void __launch_bounds__(256) trec_kernel(
    const float* __restrict__ x,
    const float* __restrict__ w_ih_up, const float* __restrict__ w_hh_up,
    const float* __restrict__ b_ih_up, const float* __restrict__ b_hh_up,
    const float* __restrict__ w1, const float* __restrict__ b1,
    const float* __restrict__ w2, const float* __restrict__ b2,
    const float* __restrict__ w_ih_dn, const float* __restrict__ w_hh_dn,
    const float* __restrict__ b_ih_dn, const float* __restrict__ b_hh_dn,
    const float* __restrict__ w_out, const float* __restrict__ b_out,
    float* __restrict__ out, int n, int half)
{
    const int tid = blockIdx.x * blockDim.x + threadIdx.x;
    if (tid >= half) return;
    const int  row1  = tid + half;
    const bool has1  = row1 < n;
    const int  row1s = has1 ? row1 : tid;   // safe address for the tail

    // ---- load both 18-float rows as 9x float2 each ----
    float xv[2][18];
    {
        const float2* xp0 = reinterpret_cast<const float2*>(x + (size_t)tid * 18u);
        const float2* xp1 = reinterpret_cast<const float2*>(x + (size_t)row1s * 18u);
        #pragma unroll
        for (int k = 0; k < 9; ++k) {
            float2 v0 = xp0[k];
            float2 v1 = xp1[k];
            xv[0][2 * k] = v0.x; xv[0][2 * k + 1] = v0.y;
            xv[1][2 * k] = v1.x; xv[1][2 * k + 1] = v1.y;
        }
    }

    // ---- hoisted uniform bias pairs (wave-uniform -> SGPRs) ----
    v2f bsum_up[4], bsum_dn[4];          // r,z gates: b_ih + b_hh pre-summed
    #pragma unroll
    for (int p = 0; p < 4; ++p) {
        bsum_up[p] = mk2(b_ih_up[2 * p], b_ih_up[2 * p + 1]) + mk2(b_hh_up[2 * p], b_hh_up[2 * p + 1]);
        bsum_dn[p] = mk2(b_ih_dn[2 * p], b_ih_dn[2 * p + 1]) + mk2(b_hh_dn[2 * p], b_hh_dn[2 * p + 1]);
    }
    const v2f bihnA_up = mk2(b_ih_up[8], b_ih_up[9]),  bihnB_up = mk2(b_ih_up[10], b_ih_up[11]);
    const v2f bhhnA_up = mk2(b_hh_up[8], b_hh_up[9]),  bhhnB_up = mk2(b_hh_up[10], b_hh_up[11]);
    const v2f bihnA_dn = mk2(b_ih_dn[8], b_ih_dn[9]),  bihnB_dn = mk2(b_ih_dn[10], b_ih_dn[11]);
    const v2f bhhnA_dn = mk2(b_hh_dn[8], b_hh_dn[9]),  bhhnB_dn = mk2(b_hh_dn[10], b_hh_dn[11]);

    v2f hA[2] = { spl(0.f), spl(0.f) }, hB[2] = { spl(0.f), spl(0.f) };
    v2f hupA[2][7], hupB[2][7];

    // ---- up GRU: i = 6..0, xi = [j[i], jd[i]] ----
    #pragma unroll
    for (int s = 0; s < 7; ++s) {
        const int i = 6 - s;
        #pragma unroll
        for (int q = 0; q < 2; ++q) {
            const v2f X0 = spl(xv[q][4 + i]);
            const v2f X1 = spl(xv[q][11 + i]);

            v2f rz[4];
            #pragma unroll
            for (int p = 0; p < 4; ++p) {      // r pairs (k=0,2), z pairs (k=4,6)
                const int k = 2 * p;
                v2f acc = bsum_up[p];
                acc = fma2(X0, mk2(w_ih_up[2 * k], w_ih_up[2 * k + 2]), acc);
                acc = fma2(X1, mk2(w_ih_up[2 * k + 1], w_ih_up[2 * k + 3]), acc);
                acc = dot4(w_hh_up, k, hA[q], hB[q], acc);
                rz[p] = acc;
            }
            v2f rA = sig2(rz[0]), rB = sig2(rz[1]);
            v2f zA = sig2(rz[2]), zB = sig2(rz[3]);

            v2f giA = bihnA_up, giB = bihnB_up;
            giA = fma2(X0, mk2(w_ih_up[16], w_ih_up[18]), giA);
            giA = fma2(X1, mk2(w_ih_up[17], w_ih_up[19]), giA);
            giB = fma2(X0, mk2(w_ih_up[20], w_ih_up[22]), giB);
            giB = fma2(X1, mk2(w_ih_up[21], w_ih_up[23]), giB);
            v2f ghA = dot4(w_hh_up, 8,  hA[q], hB[q], bhhnA_up);
            v2f ghB = dot4(w_hh_up, 10, hA[q], hB[q], bhhnB_up);
            v2f nA = tanh2(fma2(rA, ghA, giA));
            v2f nB = tanh2(fma2(rB, ghB, giB));

            hA[q] = fma2(zA, hA[q] - nA, nA);   // (1-z)*n + z*h
            hB[q] = fma2(zB, hB[q] - nB, nB);
            hupA[q][s] = hA[q]; hupB[q][s] = hB[q];
        }
    }

    // ---- MLP: tanh([obs,h] @ w1.T + b1) -> tanh(@ w2.T + b2) ----
    #pragma unroll
    for (int q = 0; q < 2; ++q) {
        float in8[8] = { xv[q][0], xv[q][1], xv[q][2], xv[q][3],
                         hA[q].x, hA[q].y, hB[q].x, hB[q].y };
        v2f a0 = mk2(b1[0], b1[1]), a1 = mk2(b1[2], b1[3]);
        #pragma unroll
        for (int d = 0; d < 8; ++d) {
            a0 = fma2(spl(in8[d]), mk2(w1[d], w1[8 + d]), a0);
            a1 = fma2(spl(in8[d]), mk2(w1[16 + d], w1[24 + d]), a1);
        }
        v2f t1A = tanh2(a0), t1B = tanh2(a1);
        v2f c0 = dot4(w2, 0, t1A, t1B, mk2(b2[0], b2[1]));
        v2f c1 = dot4(w2, 2, t1A, t1B, mk2(b2[2], b2[3]));
        hA[q] = tanh2(c0); hB[q] = tanh2(c1);
    }

    // ---- down GRU: i = 0..6, xi = hup[i]; act = [h, j[i]] @ w_out.T + b_out ----
    const float wo0 = w_out[0], wo1 = w_out[1], wo2 = w_out[2], wo3 = w_out[3], wo4 = w_out[4];
    const float bo = b_out[0];
    float acts[2][7];
    #pragma unroll
    for (int i = 0; i < 7; ++i) {
        #pragma unroll
        for (int q = 0; q < 2; ++q) {
            const v2f xiA = hupA[q][i], xiB = hupB[q][i];

            v2f rz[4];
            #pragma unroll
            for (int p = 0; p < 4; ++p) {
                const int k = 2 * p;
                v2f acc = bsum_dn[p];
                acc = dot4(w_ih_dn, k, xiA, xiB, acc);
                acc = dot4(w_hh_dn, k, hA[q], hB[q], acc);
                rz[p] = acc;
            }
            v2f rA = sig2(rz[0]), rB = sig2(rz[1]);
            v2f zA = sig2(rz[2]), zB = sig2(rz[3]);

            v2f giA = dot4(w_ih_dn, 8,  xiA, xiB, bihnA_dn);
            v2f giB = dot4(w_ih_dn, 10, xiA, xiB, bihnB_dn);
            v2f ghA = dot4(w_hh_dn, 8,  hA[q], hB[q], bhhnA_dn);
            v2f ghB = dot4(w_hh_dn, 10, hA[q], hB[q], bhhnB_dn);
            v2f nA = tanh2(fma2(rA, ghA, giA));
            v2f nB = tanh2(fma2(rB, ghB, giB));

            hA[q] = fma2(zA, hA[q] - nA, nA);
            hB[q] = fma2(zB, hB[q] - nB, nB);

            v2f t = fma2(hA[q], mk2(wo0, wo1), mk2(bo, 0.f));
            t = fma2(hB[q], mk2(wo2, wo3), t);
            acts[q][i] = fmaf(xv[q][4 + i], wo4, t.x + t.y);
        }
    }

    // ---- store (n x 7, row-major) ----
    {
        float* op0 = out + (size_t)tid * 7u;
        #pragma unroll
        for (int i = 0; i < 7; ++i) op0[i] = acts[0][i];
        if (has1) {
            float* op1 = out + (size_t)row1 * 7u;
            #pragma unroll
            for (int i = 0; i < 7; ++i) op1[i] = acts[1][i];
        }
    }
}

extern "C" void kernel_launch(void* const* d_in, const int* in_sizes, int n_in,
                              void* d_out, int out_size, void* d_ws, size_t ws_size,
                              hipStream_t stream)
{
    const float* x       = (const float*)d_in[0];
    const float* w_ih_up = (const float*)d_in[1];
    const float* w_hh_up = (const float*)d_in[2];
    const float* b_ih_up = (const float*)d_in[3];
    const float* b_hh_up = (const float*)d_in[4];
    const float* w1      = (const float*)d_in[5];
    const float* b1      = (const float*)d_in[6];
    const float* w2      = (const float*)d_in[7];
    const float* b2      = (const float*)d_in[8];
    const float* w_ih_dn = (const float*)d_in[9];
    const float* w_hh_dn = (const float*)d_in[10];
    const float* b_ih_dn = (const float*)d_in[11];
    const float* b_hh_dn = (const float*)d_in[12];
    const float* w_out   = (const float*)d_in[13];
    const float* b_out   = (const float*)d_in[14];
    float* out = (float*)d_out;

    const int n = in_sizes[0] / 18;
    const int half = (n + 1) / 2;
    const int block = 256;
    const int grid = (half + block - 1) / block;

    trec_kernel<<<grid, block, 0, stream>>>(
        x, w_ih_up, w_hh_up, b_ih_up, b_hh_up,
        w1, b1, w2, b2,
        w_ih_dn, w_hh_dn, b_ih_dn, b_hh_dn,
        w_out, b_out, out, n, half);
}

// Round 5
// 106.200 us; speedup vs baseline: 1.2529x; 1.2430x over previous
//
#include <hip/hip_runtime.h>

// TRecPolicy round 5: round-2 packed math + weight pre-pack into d_ws so every
// v_pk_fma weight operand is a memory-adjacent (-> SGPR-pair) constant.
// Kernel 1 (repack, 131 threads, runs every call): build packed param block.
// Kernel 2: per-row fused net, 1 row/thread, reads packed params uniformly.

typedef float v2f __attribute__((ext_vector_type(2)));

__device__ __forceinline__ v2f mk2(float a, float b) { v2f r; r.x = a; r.y = b; return r; }
__device__ __forceinline__ v2f spl(float s) { return mk2(s, s); }
__device__ __forceinline__ v2f fma2(v2f a, v2f b, v2f c) { return __builtin_elementwise_fma(a, b, c); }

__device__ __forceinline__ float fexp2(float x) {
#if __has_builtin(__builtin_amdgcn_exp2f)
    return __builtin_amdgcn_exp2f(x);          // v_exp_f32 (2^x)
#else
    return __expf(0.6931471805599453f * x);
#endif
}
__device__ __forceinline__ float frcp(float x) { return __builtin_amdgcn_rcpf(x); }

#define LOG2E 1.44269504088896f

__device__ __forceinline__ v2f sig2(v2f g) {           // 1/(1+2^(-x*log2e))
    v2f t = g * spl(-LOG2E);
    v2f e = mk2(fexp2(t.x), fexp2(t.y));
    v2f d = e + spl(1.0f);
    return mk2(frcp(d.x), frcp(d.y));
}
__device__ __forceinline__ v2f tanh2(v2f g) {          // 2/(1+2^(-2x*log2e)) - 1
    v2f t = g * spl(-2.0f * LOG2E);
    v2f e = mk2(fexp2(t.x), fexp2(t.y));
    v2f d = e + spl(1.0f);
    v2f r = mk2(frcp(d.x), frcp(d.y));
    return fma2(r, spl(2.0f), spl(-1.0f));
}

// Packed parameter block layout (all v2f, 131 total). Pair pp covers output
// rows (2pp, 2pp+1); element [pp][c] = {W[2pp][c], W[2pp+1][c]}.
struct PK {
    v2f wiu[6][2];   // off   0: w_ih_up (12x2)
    v2f whu[6][4];   // off  12: w_hh_up (12x4)
    v2f wid[6][4];   // off  36: w_ih_dn (12x4)
    v2f whd[6][4];   // off  60: w_hh_dn (12x4)
    v2f w1p[2][8];   // off  84: w1 (4x8)
    v2f w2p[2][4];   // off 100: w2 (4x4)
    v2f bsu[4];      // off 108: b_ih_up+b_hh_up rows 0..7, pre-summed
    v2f bsd[4];      // off 112: b_ih_dn+b_hh_dn rows 0..7, pre-summed
    v2f binu[2];     // off 116: b_ih_up rows 8..11
    v2f bhnu[2];     // off 118: b_hh_up rows 8..11
    v2f bind[2];     // off 120: b_ih_dn rows 8..11
    v2f bhnd[2];     // off 122: b_hh_dn rows 8..11
    v2f b1p[2];      // off 124
    v2f b2p[2];      // off 126
    v2f wo01;        // off 128: {w_out[0], w_out[1]}
    v2f wo23;        // off 129: {w_out[2], w_out[3]}
    v2f wo4bo;       // off 130: {w_out[4], b_out[0]}
};

__global__ void repack_kernel(
    const float* __restrict__ w_ih_up, const float* __restrict__ w_hh_up,
    const float* __restrict__ b_ih_up, const float* __restrict__ b_hh_up,
    const float* __restrict__ w1, const float* __restrict__ b1,
    const float* __restrict__ w2, const float* __restrict__ b2,
    const float* __restrict__ w_ih_dn, const float* __restrict__ w_hh_dn,
    const float* __restrict__ b_ih_dn, const float* __restrict__ b_hh_dn,
    const float* __restrict__ w_out, const float* __restrict__ b_out,
    float2* __restrict__ pk)
{
    const int t = threadIdx.x;
    if (t < 12)       { int pp = t >> 1, c = t & 1;          pk[t] = make_float2(w_ih_up[4*pp+c],  w_ih_up[4*pp+2+c]); }
    else if (t < 36)  { int i = t-12, pp = i >> 2, c = i & 3; pk[t] = make_float2(w_hh_up[8*pp+c],  w_hh_up[8*pp+4+c]); }
    else if (t < 60)  { int i = t-36, pp = i >> 2, c = i & 3; pk[t] = make_float2(w_ih_dn[8*pp+c],  w_ih_dn[8*pp+4+c]); }
    else if (t < 84)  { int i = t-60, pp = i >> 2, c = i & 3; pk[t] = make_float2(w_hh_dn[8*pp+c],  w_hh_dn[8*pp+4+c]); }
    else if (t < 100) { int i = t-84, pp = i >> 3, c = i & 7; pk[t] = make_float2(w1[16*pp+c],      w1[16*pp+8+c]); }
    else if (t < 108) { int i = t-100, pp = i >> 2, c = i & 3; pk[t] = make_float2(w2[8*pp+c],      w2[8*pp+4+c]); }
    else if (t < 112) { int p = t-108; pk[t] = make_float2(b_ih_up[2*p] + b_hh_up[2*p], b_ih_up[2*p+1] + b_hh_up[2*p+1]); }
    else if (t < 116) { int p = t-112; pk[t] = make_float2(b_ih_dn[2*p] + b_hh_dn[2*p], b_ih_dn[2*p+1] + b_hh_dn[2*p+1]); }
    else if (t < 118) { int p = t-116; pk[t] = make_float2(b_ih_up[8+2*p], b_ih_up[9+2*p]); }
    else if (t < 120) { int p = t-118; pk[t] = make_float2(b_hh_up[8+2*p], b_hh_up[9+2*p]); }
    else if (t < 122) { int p = t-120; pk[t] = make_float2(b_ih_dn[8+2*p], b_ih_dn[9+2*p]); }
    else if (t < 124) { int p = t-122; pk[t] = make_float2(b_hh_dn[8+2*p], b_hh_dn[9+2*p]); }
    else if (t < 126) { int p = t-124; pk[t] = make_float2(b1[2*p], b1[2*p+1]); }
    else if (t < 128) { int p = t-126; pk[t] = make_float2(b2[2*p], b2[2*p+1]); }
    else if (t == 128) pk[t] = make_float2(w_out[0], w_out[1]);
    else if (t == 129) pk[t] = make_float2(w_out[2], w_out[3]);
    else if (t == 130) pk[t] = make_float2(w_out[4], b_out[0]);
}

// acc += pair-packed 4-dot: wp[c] = {W[2pp][c], W[2pp+1][c]}, input (a.x,a.y,b.x,b.y)
__device__ __forceinline__ v2f dot4p(const v2f* __restrict__ wp, v2f a, v2f b, v2f acc) {
    acc = fma2(spl(a.x), wp[0], acc);
    acc = fma2(spl(a.y), wp[1], acc);
    acc = fma2(spl(b.x), wp[2], acc);
    acc = fma2(spl(b.y), wp[3], acc);
    return acc;
}

__global__ void __launch_bounds__(256) trec_kernel(
    const float* __restrict__ x, const PK* __restrict__ pk,
    float* __restrict__ out, int n)
{
    const int row = blockIdx.x * blockDim.x + threadIdx.x;
    if (row >= n) return;

    // ---- load 18-float row as 9x float2 ----
    float xv[18];
    {
        const float2* xp = reinterpret_cast<const float2*>(x + (size_t)row * 18u);
        #pragma unroll
        for (int k = 0; k < 9; ++k) {
            float2 v = xp[k];
            xv[2 * k] = v.x;
            xv[2 * k + 1] = v.y;
        }
    }

    v2f hA = spl(0.f), hB = spl(0.f);
    v2f hupA[7], hupB[7];

    // ---- up GRU: i = 6..0, xi = [j[i], jd[i]] ----
    #pragma unroll
    for (int s = 0; s < 7; ++s) {
        const int i = 6 - s;
        const v2f X0 = spl(xv[4 + i]);
        const v2f X1 = spl(xv[11 + i]);

        v2f rz[4];
        #pragma unroll
        for (int p = 0; p < 4; ++p) {          // pairs: rows (0,1),(2,3)=r; (4,5),(6,7)=z
            v2f acc = pk->bsu[p];
            acc = fma2(X0, pk->wiu[p][0], acc);
            acc = fma2(X1, pk->wiu[p][1], acc);
            acc = dot4p(pk->whu[p], hA, hB, acc);
            rz[p] = acc;
        }
        v2f rA = sig2(rz[0]), rB = sig2(rz[1]);
        v2f zA = sig2(rz[2]), zB = sig2(rz[3]);

        // n gates: rows (8,9),(10,11); gi and gh separate for r * gh
        v2f giA = fma2(X1, pk->wiu[4][1], fma2(X0, pk->wiu[4][0], pk->binu[0]));
        v2f giB = fma2(X1, pk->wiu[5][1], fma2(X0, pk->wiu[5][0], pk->binu[1]));
        v2f ghA = dot4p(pk->whu[4], hA, hB, pk->bhnu[0]);
        v2f ghB = dot4p(pk->whu[5], hA, hB, pk->bhnu[1]);
        v2f nA = tanh2(fma2(rA, ghA, giA));
        v2f nB = tanh2(fma2(rB, ghB, giB));

        hA = fma2(zA, hA - nA, nA);            // (1-z)*n + z*h
        hB = fma2(zB, hB - nB, nB);
        hupA[s] = hA; hupB[s] = hB;
    }

    // ---- MLP: tanh([obs,h] @ w1.T + b1) -> tanh(@ w2.T + b2) ----
    {
        float in8[8] = { xv[0], xv[1], xv[2], xv[3], hA.x, hA.y, hB.x, hB.y };
        v2f a0 = pk->b1p[0], a1 = pk->b1p[1];
        #pragma unroll
        for (int d = 0; d < 8; ++d) {
            a0 = fma2(spl(in8[d]), pk->w1p[0][d], a0);
            a1 = fma2(spl(in8[d]), pk->w1p[1][d], a1);
        }
        v2f t1A = tanh2(a0), t1B = tanh2(a1);
        v2f c0 = dot4p(pk->w2p[0], t1A, t1B, pk->b2p[0]);
        v2f c1 = dot4p(pk->w2p[1], t1A, t1B, pk->b2p[1]);
        hA = tanh2(c0); hB = tanh2(c1);
    }

    // ---- down GRU: i = 0..6, xi = hup[i]; act = [h, j[i]] @ w_out.T + b_out ----
    float acts[7];
    #pragma unroll
    for (int i = 0; i < 7; ++i) {
        const v2f xiA = hupA[i], xiB = hupB[i];

        v2f rz[4];
        #pragma unroll
        for (int p = 0; p < 4; ++p) {
            v2f acc = pk->bsd[p];
            acc = dot4p(pk->wid[p], xiA, xiB, acc);
            acc = dot4p(pk->whd[p], hA, hB, acc);
            rz[p] = acc;
        }
        v2f rA = sig2(rz[0]), rB = sig2(rz[1]);
        v2f zA = sig2(rz[2]), zB = sig2(rz[3]);

        v2f giA = dot4p(pk->wid[4], xiA, xiB, pk->bind[0]);
        v2f giB = dot4p(pk->wid[5], xiA, xiB, pk->bind[1]);
        v2f ghA = dot4p(pk->whd[4], hA, hB, pk->bhnd[0]);
        v2f ghB = dot4p(pk->whd[5], hA, hB, pk->bhnd[1]);
        v2f nA = tanh2(fma2(rA, ghA, giA));
        v2f nB = tanh2(fma2(rB, ghB, giB));

        hA = fma2(zA, hA - nA, nA);
        hB = fma2(zB, hB - nB, nB);

        v2f t = fma2(hA, pk->wo01, mk2(pk->wo4bo.y, 0.f));
        t = fma2(hB, pk->wo23, t);
        acts[i] = fmaf(xv[4 + i], pk->wo4bo.x, t.x + t.y);
    }

    // ---- store (n x 7, row-major) ----
    float* op = out + (size_t)row * 7u;
    #pragma unroll
    for (int i = 0; i < 7; ++i) op[i] = acts[i];
}

extern "C" void kernel_launch(void* const* d_in, const int* in_sizes, int n_in,
                              void* d_out, int out_size, void* d_ws, size_t ws_size,
                              hipStream_t stream)
{
    const float* x       = (const float*)d_in[0];
    const float* w_ih_up = (const float*)d_in[1];
    const float* w_hh_up = (const float*)d_in[2];
    const float* b_ih_up = (const float*)d_in[3];
    const float* b_hh_up = (const float*)d_in[4];
    const float* w1      = (const float*)d_in[5];
    const float* b1      = (const float*)d_in[6];
    const float* w2      = (const float*)d_in[7];
    const float* b2      = (const float*)d_in[8];
    const float* w_ih_dn = (const float*)d_in[9];
    const float* w_hh_dn = (const float*)d_in[10];
    const float* b_ih_dn = (const float*)d_in[11];
    const float* b_hh_dn = (const float*)d_in[12];
    const float* w_out   = (const float*)d_in[13];
    const float* b_out   = (const float*)d_in[14];
    float* out = (float*)d_out;

    const int n = in_sizes[0] / 18;
    const int block = 256;
    const int grid = (n + block - 1) / block;

    repack_kernel<<<1, 192, 0, stream>>>(
        w_ih_up, w_hh_up, b_ih_up, b_hh_up,
        w1, b1, w2, b2,
        w_ih_dn, w_hh_dn, b_ih_dn, b_hh_dn,
        w_out, b_out, (float2*)d_ws);

    trec_kernel<<<grid, block, 0, stream>>>(
        x, (const PK*)d_ws, out, n);
}